// Round 4
// baseline (63.481 us; speedup 1.0000x reference)
//
#include <hip/hip_runtime.h>
#include <math.h>

constexpr int NB = 8192;   // batch
constexpr int ND = 1024;   // dim
constexpr int NK = 30;     // negatives

typedef __attribute__((ext_vector_type(2))) float vf2;

__device__ __forceinline__ int pack4_fp8(float a, float b, float c, float d) {
    int t = 0;
    t = __builtin_amdgcn_cvt_pk_fp8_f32(a, b, t, false);
    t = __builtin_amdgcn_cvt_pk_fp8_f32(c, d, t, true);
    return t;
}

// ---------------------------------------------------------------------------
// Kernel 1: normalize rows of [z_i; z_j] -> fp8 e4m3 pool [2B, D] (16 MiB).
// One wave per row; lane owns 16 contiguous elements (lane*16 .. +15).
// ---------------------------------------------------------------------------
__global__ void normalize_fp8_kernel(const float* __restrict__ zi,
                                     const float* __restrict__ zj,
                                     int* __restrict__ pool) {
    int row  = blockIdx.x * 4 + (threadIdx.x >> 6);
    int lane = threadIdx.x & 63;
    const float* src = (row < NB) ? (zi + (size_t)row * ND)
                                  : (zj + (size_t)(row - NB) * ND);
    float v[16];
    float s = 0.f;
#pragma unroll
    for (int seg = 0; seg < 4; ++seg) {
        float4 t = *reinterpret_cast<const float4*>(src + lane * 16 + seg * 4);
        v[seg * 4 + 0] = t.x; v[seg * 4 + 1] = t.y;
        v[seg * 4 + 2] = t.z; v[seg * 4 + 3] = t.w;
        s += t.x * t.x + t.y * t.y + t.z * t.z + t.w * t.w;
    }
#pragma unroll
    for (int off = 32; off >= 1; off >>= 1)
        s += __shfl_xor(s, off, 64);
    float inv = 1.f / fmaxf(sqrtf(s), 1e-12f);

    int4 w;
    w.x = pack4_fp8(v[0] * inv,  v[1] * inv,  v[2] * inv,  v[3] * inv);
    w.y = pack4_fp8(v[4] * inv,  v[5] * inv,  v[6] * inv,  v[7] * inv);
    w.z = pack4_fp8(v[8] * inv,  v[9] * inv,  v[10] * inv, v[11] * inv);
    w.w = pack4_fp8(v[12] * inv, v[13] * inv, v[14] * inv, v[15] * inv);
    *reinterpret_cast<int4*>(pool + row * (ND / 4) + lane * 4) = w;
}

// ---------------------------------------------------------------------------
// Kernel 2: per-row loss. One wave per row; double-buffered chunks of 4
// gathers (steady-state depth 4-8 outstanding row-fetches per wave).
// __launch_bounds__(256,8) caps VGPR at 64 -> 8 blocks/CU.
// ---------------------------------------------------------------------------
__global__ void __launch_bounds__(256, 8)
loss_kernel(const int* __restrict__ pool,
            const int* __restrict__ neg_idx,
            const float* __restrict__ temp_ptr,
            float* __restrict__ partial) {
    int wave = threadIdx.x >> 6;
    int lane = threadIdx.x & 63;
    int row  = blockIdx.x * 4 + wave;

    float inv_t = 1.f / temp_ptr[0];

    // a-row (quantized, normalized) -> 16 floats in registers
    float af[16];
    {
        int4 araw = *reinterpret_cast<const int4*>(pool + row * 256 + lane * 4);
        const int* ap = reinterpret_cast<const int*>(&araw);
#pragma unroll
        for (int d = 0; d < 4; ++d) {
            vf2 lo = __builtin_amdgcn_cvt_pk_f32_fp8(ap[d], false);
            vf2 hi = __builtin_amdgcn_cvt_pk_f32_fp8(ap[d], true);
            af[d * 4 + 0] = lo[0]; af[d * 4 + 1] = lo[1];
            af[d * 4 + 2] = hi[0]; af[d * 4 + 3] = hi[1];
        }
    }

    int myidx = (lane < NK) ? neg_idx[row * NK + lane] : 0;

    float m = -INFINITY, ssum = 0.f, logit0 = 0.f;

    int4 bufA[4], bufB[4];

    // k = 0 is the positive (row+NB), k = 1..30 are negatives. 31 total.
    auto issue = [&](int kc, int4* buf) {
#pragma unroll
        for (int j = 0; j < 4; ++j) {
            int kk = kc + j;
            if (kk < 31) {
                int r = (kk == 0) ? (row + NB) : __shfl(myidx, kk - 1, 64);
                buf[j] = *reinterpret_cast<const int4*>(pool + r * 256 + lane * 4);
            }
        }
    };
    auto consume = [&](int kc, const int4* buf) {
#pragma unroll
        for (int j = 0; j < 4; ++j) {
            int kk = kc + j;
            if (kk < 31) {
                const int* rp = reinterpret_cast<const int*>(&buf[j]);
                float dot = 0.f;
#pragma unroll
                for (int d = 0; d < 4; ++d) {
                    vf2 lo = __builtin_amdgcn_cvt_pk_f32_fp8(rp[d], false);
                    vf2 hi = __builtin_amdgcn_cvt_pk_f32_fp8(rp[d], true);
                    dot += af[d * 4 + 0] * lo[0] + af[d * 4 + 1] * lo[1]
                         + af[d * 4 + 2] * hi[0] + af[d * 4 + 3] * hi[1];
                }
#pragma unroll
                for (int off = 32; off >= 1; off >>= 1)
                    dot += __shfl_xor(dot, off, 64);
                float logit = dot * inv_t;
                if (kk == 0) {
                    logit0 = logit; m = logit; ssum = 1.f;
                } else if (logit > m) {
                    ssum = ssum * __expf(m - logit) + 1.f; m = logit;
                } else {
                    ssum += __expf(logit - m);
                }
            }
        }
    };

    issue(0, bufA);
    issue(4, bufB);
#pragma unroll
    for (int kc = 0; kc < 31; kc += 8) {
        consume(kc, bufA);
        if (kc + 8 < 31) issue(kc + 8, bufA);
        consume(kc + 4, bufB);
        if (kc + 12 < 31) issue(kc + 12, bufB);
    }

    float loss = (m + logf(ssum)) - logit0;

    __shared__ float red[4];
    if (lane == 0) red[wave] = loss;
    __syncthreads();
    if (threadIdx.x == 0)
        partial[blockIdx.x] = red[0] + red[1] + red[2] + red[3];
}

// ---------------------------------------------------------------------------
// Fallback f32 path (only if ws_size is too small for the fp8 pool)
// ---------------------------------------------------------------------------
__global__ void norms_kernel(const float* __restrict__ zi,
                             const float* __restrict__ zj,
                             float* __restrict__ inv_norm) {
    int row  = blockIdx.x * 4 + (threadIdx.x >> 6);
    int lane = threadIdx.x & 63;
    if (row >= 2 * NB) return;
    const float* src = (row < NB) ? (zi + (size_t)row * ND)
                                  : (zj + (size_t)(row - NB) * ND);
    float s = 0.f;
#pragma unroll
    for (int seg = 0; seg < 4; ++seg) {
        float4 v = *reinterpret_cast<const float4*>(src + seg * 256 + lane * 4);
        s += v.x * v.x + v.y * v.y + v.z * v.z + v.w * v.w;
    }
#pragma unroll
    for (int off = 32; off >= 1; off >>= 1)
        s += __shfl_xor(s, off, 64);
    if (lane == 0)
        inv_norm[row] = 1.f / fmaxf(sqrtf(s), 1e-12f);
}

__global__ void loss_kernel_f32(const float* __restrict__ zi,
                                const float* __restrict__ zj,
                                const int*   __restrict__ neg_idx,
                                const float* __restrict__ temp_ptr,
                                const float* __restrict__ inv_norm,
                                float* __restrict__ partial) {
    int wave = threadIdx.x >> 6;
    int lane = threadIdx.x & 63;
    int row  = blockIdx.x * 4 + wave;

    float inv_t = 1.f / temp_ptr[0];
    const float* a = zi + (size_t)row * ND;

    float4 av[4];
#pragma unroll
    for (int seg = 0; seg < 4; ++seg)
        av[seg] = *reinterpret_cast<const float4*>(a + seg * 256 + lane * 4);

    float inv_a = inv_norm[row];
    float m = -INFINITY, ssum = 0.f, logit0 = 0.f;

    for (int k = -1; k < NK; ++k) {
        int r = (k < 0) ? (row + NB) : neg_idx[row * NK + k];
        const float* bp = (r < NB) ? (zi + (size_t)r * ND)
                                   : (zj + (size_t)(r - NB) * ND);
        float inv_b = inv_norm[r];
        float dot = 0.f;
#pragma unroll
        for (int seg = 0; seg < 4; ++seg) {
            float4 bv = *reinterpret_cast<const float4*>(bp + seg * 256 + lane * 4);
            dot += av[seg].x * bv.x + av[seg].y * bv.y
                 + av[seg].z * bv.z + av[seg].w * bv.w;
        }
#pragma unroll
        for (int off = 32; off >= 1; off >>= 1)
            dot += __shfl_xor(dot, off, 64);
        float logit = dot * inv_a * inv_b * inv_t;
        if (k < 0) logit0 = logit;
        if (logit > m) { ssum = ssum * __expf(m - logit) + 1.f; m = logit; }
        else           { ssum += __expf(logit - m); }
    }
    float loss = (m + logf(ssum)) - logit0;

    __shared__ float red[4];
    if (lane == 0) red[wave] = loss;
    __syncthreads();
    if (threadIdx.x == 0)
        partial[blockIdx.x] = red[0] + red[1] + red[2] + red[3];
}

// ---------------------------------------------------------------------------
// Kernel 3: final reduction of per-block partials -> mean loss
// ---------------------------------------------------------------------------
__global__ void reduce_kernel(const float* __restrict__ partial, int n,
                              float* __restrict__ out) {
    float s = 0.f;
    for (int i = threadIdx.x; i < n; i += 256) s += partial[i];
#pragma unroll
    for (int off = 32; off >= 1; off >>= 1)
        s += __shfl_xor(s, off, 64);
    __shared__ float lds[4];
    int wave = threadIdx.x >> 6, lane = threadIdx.x & 63;
    if (lane == 0) lds[wave] = s;
    __syncthreads();
    if (threadIdx.x == 0)
        out[0] = (lds[0] + lds[1] + lds[2] + lds[3]) * (1.f / (float)NB);
}

extern "C" void kernel_launch(void* const* d_in, const int* in_sizes, int n_in,
                              void* d_out, int out_size, void* d_ws, size_t ws_size,
                              hipStream_t stream) {
    const float* zi      = (const float*)d_in[0];
    const float* zj      = (const float*)d_in[1];
    const float* temp    = (const float*)d_in[2];
    const int*   neg_idx = (const int*)d_in[3];
    float* out = (float*)d_out;

    const size_t pool_bytes    = (size_t)2 * NB * ND;            // fp8: 16 MiB
    const size_t partial_bytes = (size_t)(NB / 4) * sizeof(float);

    if (ws_size >= pool_bytes + partial_bytes) {
        int*   pool    = (int*)d_ws;
        float* partial = (float*)((char*)d_ws + pool_bytes);

        normalize_fp8_kernel<<<(2 * NB) / 4, 256, 0, stream>>>(zi, zj, pool);
        loss_kernel<<<NB / 4, 256, 0, stream>>>(pool, neg_idx, temp, partial);
        reduce_kernel<<<1, 256, 0, stream>>>(partial, NB / 4, out);
    } else {
        float* inv_norm = (float*)d_ws;              // 2B floats
        float* partial  = inv_norm + 2 * NB;         // B/4 floats

        norms_kernel<<<(2 * NB) / 4, 256, 0, stream>>>(zi, zj, inv_norm);
        loss_kernel_f32<<<NB / 4, 256, 0, stream>>>(zi, zj, neg_idx, temp,
                                                    inv_norm, partial);
        reduce_kernel<<<1, 256, 0, stream>>>(partial, NB / 4, out);
    }
}

// Round 5
// 57.570 us; speedup vs baseline: 1.1027x; 1.1027x over previous
//
#include <hip/hip_runtime.h>
#include <math.h>

constexpr int NB = 8192;   // batch
constexpr int ND = 1024;   // dim
constexpr int NK = 30;     // negatives

typedef __attribute__((ext_vector_type(2))) float vf2;

__device__ __forceinline__ int pack4_fp8(float a, float b, float c, float d) {
    int t = 0;
    t = __builtin_amdgcn_cvt_pk_fp8_f32(a, b, t, false);
    t = __builtin_amdgcn_cvt_pk_fp8_f32(c, d, t, true);
    return t;
}

// ---------------------------------------------------------------------------
// Kernel 1: normalize rows of [z_i; z_j] -> fp8 e4m3 pool [2B, D] (16 MiB).
// One wave per row; lane owns 16 contiguous elements (lane*16 .. +15).
// ---------------------------------------------------------------------------
__global__ void normalize_fp8_kernel(const float* __restrict__ zi,
                                     const float* __restrict__ zj,
                                     int* __restrict__ pool) {
    int row  = blockIdx.x * 4 + (threadIdx.x >> 6);
    int lane = threadIdx.x & 63;
    const float* src = (row < NB) ? (zi + (size_t)row * ND)
                                  : (zj + (size_t)(row - NB) * ND);
    float v[16];
    float s = 0.f;
#pragma unroll
    for (int seg = 0; seg < 4; ++seg) {
        float4 t = *reinterpret_cast<const float4*>(src + lane * 16 + seg * 4);
        v[seg * 4 + 0] = t.x; v[seg * 4 + 1] = t.y;
        v[seg * 4 + 2] = t.z; v[seg * 4 + 3] = t.w;
        s += t.x * t.x + t.y * t.y + t.z * t.z + t.w * t.w;
    }
#pragma unroll
    for (int off = 32; off >= 1; off >>= 1)
        s += __shfl_xor(s, off, 64);
    float inv = 1.f / fmaxf(sqrtf(s), 1e-12f);

    int4 w;
    w.x = pack4_fp8(v[0] * inv,  v[1] * inv,  v[2] * inv,  v[3] * inv);
    w.y = pack4_fp8(v[4] * inv,  v[5] * inv,  v[6] * inv,  v[7] * inv);
    w.z = pack4_fp8(v[8] * inv,  v[9] * inv,  v[10] * inv, v[11] * inv);
    w.w = pack4_fp8(v[12] * inv, v[13] * inv, v[14] * inv, v[15] * inv);
    *reinterpret_cast<int4*>(pool + row * (ND / 4) + lane * 4) = w;
}

// ---------------------------------------------------------------------------
// Kernel 2: per-row loss. One wave per row. No cross-lane ops inside the
// k-loop: each lane accumulates private partial dots dt[0..30]; all 31
// butterfly reductions run batched (independent) at the end, then a
// register-resident logsumexp. Loads are free to pipeline deeply.
// ---------------------------------------------------------------------------
__global__ void loss_kernel(const int* __restrict__ pool,
                            const int* __restrict__ neg_idx,
                            const float* __restrict__ temp_ptr,
                            float* __restrict__ partial) {
    int wave = threadIdx.x >> 6;
    int lane = threadIdx.x & 63;
    int row  = blockIdx.x * 4 + wave;

    float inv_t = 1.f / temp_ptr[0];

    // a-row (quantized, normalized) -> 16 floats in registers
    float af[16];
    {
        int4 araw = *reinterpret_cast<const int4*>(pool + row * 256 + lane * 4);
        const int* ap = reinterpret_cast<const int*>(&araw);
#pragma unroll
        for (int d = 0; d < 4; ++d) {
            vf2 lo = __builtin_amdgcn_cvt_pk_f32_fp8(ap[d], false);
            vf2 hi = __builtin_amdgcn_cvt_pk_f32_fp8(ap[d], true);
            af[d * 4 + 0] = lo[0]; af[d * 4 + 1] = lo[1];
            af[d * 4 + 2] = hi[0]; af[d * 4 + 3] = hi[1];
        }
    }

    int myidx = (lane < NK) ? neg_idx[row * NK + lane] : 0;

    // k = 0 positive (row+NB), k = 1..30 negatives. Private partial dots.
    float dt[31];

#pragma unroll
    for (int kc = 0; kc < 31; kc += 8) {
        int4 raw[8];
#pragma unroll
        for (int j = 0; j < 8; ++j) {
            int kk = kc + j;
            if (kk < 31) {
                int r = (kk == 0) ? (row + NB) : __shfl(myidx, kk - 1, 64);
                raw[j] = *reinterpret_cast<const int4*>(pool + r * 256 + lane * 4);
            }
        }
#pragma unroll
        for (int j = 0; j < 8; ++j) {
            int kk = kc + j;
            if (kk < 31) {
                const int* rp = reinterpret_cast<const int*>(&raw[j]);
                float d0 = 0.f;
#pragma unroll
                for (int d = 0; d < 4; ++d) {
                    vf2 lo = __builtin_amdgcn_cvt_pk_f32_fp8(rp[d], false);
                    vf2 hi = __builtin_amdgcn_cvt_pk_f32_fp8(rp[d], true);
                    d0 += af[d * 4 + 0] * lo[0] + af[d * 4 + 1] * lo[1]
                        + af[d * 4 + 2] * hi[0] + af[d * 4 + 3] * hi[1];
                }
                dt[kk] = d0;
            }
        }
    }

    // Batched cross-lane reduction: 31 independent butterflies.
#pragma unroll
    for (int k = 0; k < 31; ++k) {
#pragma unroll
        for (int off = 32; off >= 1; off >>= 1)
            dt[k] += __shfl_xor(dt[k], off, 64);
    }

    // Register-resident logsumexp (redundant across lanes).
    float logit0 = dt[0] * inv_t;
    float m = logit0;
#pragma unroll
    for (int k = 1; k < 31; ++k) m = fmaxf(m, dt[k] * inv_t);
    float ssum = 0.f;
#pragma unroll
    for (int k = 0; k < 31; ++k) ssum += __expf(dt[k] * inv_t - m);
    float loss = (m + logf(ssum)) - logit0;

    __shared__ float red[4];
    if (lane == 0) red[wave] = loss;
    __syncthreads();
    if (threadIdx.x == 0)
        partial[blockIdx.x] = red[0] + red[1] + red[2] + red[3];
}

// ---------------------------------------------------------------------------
// Fallback f32 path (only if ws_size is too small for the fp8 pool)
// ---------------------------------------------------------------------------
__global__ void norms_kernel(const float* __restrict__ zi,
                             const float* __restrict__ zj,
                             float* __restrict__ inv_norm) {
    int row  = blockIdx.x * 4 + (threadIdx.x >> 6);
    int lane = threadIdx.x & 63;
    if (row >= 2 * NB) return;
    const float* src = (row < NB) ? (zi + (size_t)row * ND)
                                  : (zj + (size_t)(row - NB) * ND);
    float s = 0.f;
#pragma unroll
    for (int seg = 0; seg < 4; ++seg) {
        float4 v = *reinterpret_cast<const float4*>(src + seg * 256 + lane * 4);
        s += v.x * v.x + v.y * v.y + v.z * v.z + v.w * v.w;
    }
#pragma unroll
    for (int off = 32; off >= 1; off >>= 1)
        s += __shfl_xor(s, off, 64);
    if (lane == 0)
        inv_norm[row] = 1.f / fmaxf(sqrtf(s), 1e-12f);
}

__global__ void loss_kernel_f32(const float* __restrict__ zi,
                                const float* __restrict__ zj,
                                const int*   __restrict__ neg_idx,
                                const float* __restrict__ temp_ptr,
                                const float* __restrict__ inv_norm,
                                float* __restrict__ partial) {
    int wave = threadIdx.x >> 6;
    int lane = threadIdx.x & 63;
    int row  = blockIdx.x * 4 + wave;

    float inv_t = 1.f / temp_ptr[0];
    const float* a = zi + (size_t)row * ND;

    float4 av[4];
#pragma unroll
    for (int seg = 0; seg < 4; ++seg)
        av[seg] = *reinterpret_cast<const float4*>(a + seg * 256 + lane * 4);

    float inv_a = inv_norm[row];
    float m = -INFINITY, ssum = 0.f, logit0 = 0.f;

    for (int k = -1; k < NK; ++k) {
        int r = (k < 0) ? (row + NB) : neg_idx[row * NK + k];
        const float* bp = (r < NB) ? (zi + (size_t)r * ND)
                                   : (zj + (size_t)(r - NB) * ND);
        float inv_b = inv_norm[r];
        float dot = 0.f;
#pragma unroll
        for (int seg = 0; seg < 4; ++seg) {
            float4 bv = *reinterpret_cast<const float4*>(bp + seg * 256 + lane * 4);
            dot += av[seg].x * bv.x + av[seg].y * bv.y
                 + av[seg].z * bv.z + av[seg].w * bv.w;
        }
#pragma unroll
        for (int off = 32; off >= 1; off >>= 1)
            dot += __shfl_xor(dot, off, 64);
        float logit = dot * inv_a * inv_b * inv_t;
        if (k < 0) logit0 = logit;
        if (logit > m) { ssum = ssum * __expf(m - logit) + 1.f; m = logit; }
        else           { ssum += __expf(logit - m); }
    }
    float loss = (m + logf(ssum)) - logit0;

    __shared__ float red[4];
    if (lane == 0) red[wave] = loss;
    __syncthreads();
    if (threadIdx.x == 0)
        partial[blockIdx.x] = red[0] + red[1] + red[2] + red[3];
}

// ---------------------------------------------------------------------------
// Kernel 3: final reduction of per-block partials -> mean loss
// ---------------------------------------------------------------------------
__global__ void reduce_kernel(const float* __restrict__ partial, int n,
                              float* __restrict__ out) {
    float s = 0.f;
    for (int i = threadIdx.x; i < n; i += 256) s += partial[i];
#pragma unroll
    for (int off = 32; off >= 1; off >>= 1)
        s += __shfl_xor(s, off, 64);
    __shared__ float lds[4];
    int wave = threadIdx.x >> 6, lane = threadIdx.x & 63;
    if (lane == 0) lds[wave] = s;
    __syncthreads();
    if (threadIdx.x == 0)
        out[0] = (lds[0] + lds[1] + lds[2] + lds[3]) * (1.f / (float)NB);
}

extern "C" void kernel_launch(void* const* d_in, const int* in_sizes, int n_in,
                              void* d_out, int out_size, void* d_ws, size_t ws_size,
                              hipStream_t stream) {
    const float* zi      = (const float*)d_in[0];
    const float* zj      = (const float*)d_in[1];
    const float* temp    = (const float*)d_in[2];
    const int*   neg_idx = (const int*)d_in[3];
    float* out = (float*)d_out;

    const size_t pool_bytes    = (size_t)2 * NB * ND;            // fp8: 16 MiB
    const size_t partial_bytes = (size_t)(NB / 4) * sizeof(float);

    if (ws_size >= pool_bytes + partial_bytes) {
        int*   pool    = (int*)d_ws;
        float* partial = (float*)((char*)d_ws + pool_bytes);

        normalize_fp8_kernel<<<(2 * NB) / 4, 256, 0, stream>>>(zi, zj, pool);
        loss_kernel<<<NB / 4, 256, 0, stream>>>(pool, neg_idx, temp, partial);
        reduce_kernel<<<1, 256, 0, stream>>>(partial, NB / 4, out);
    } else {
        float* inv_norm = (float*)d_ws;              // 2B floats
        float* partial  = inv_norm + 2 * NB;         // B/4 floats

        norms_kernel<<<(2 * NB) / 4, 256, 0, stream>>>(zi, zj, inv_norm);
        loss_kernel_f32<<<NB / 4, 256, 0, stream>>>(zi, zj, neg_idx, temp,
                                                    inv_norm, partial);
        reduce_kernel<<<1, 256, 0, stream>>>(partial, NB / 4, out);
    }
}

// Round 6
// 51.889 us; speedup vs baseline: 1.2234x; 1.1095x over previous
//
#include <hip/hip_runtime.h>
#include <math.h>

constexpr int NB = 8192;   // batch
constexpr int ND = 1024;   // dim
constexpr int NK = 30;     // negatives

typedef __attribute__((ext_vector_type(2))) float vf2;

#if defined(__has_builtin)
#  if __has_builtin(__builtin_amdgcn_sdot4)
#    define HAVE_SDOT4 1
#  endif
#endif
#ifndef HAVE_SDOT4
#  define HAVE_SDOT4 0
#endif

// ===========================================================================
// Primary path: int8 pool + v_dot4_i32_i8
// ===========================================================================
#if HAVE_SDOT4

__device__ __forceinline__ int pack4_i8(float a, float b, float c, float d) {
    int x0 = (int)rintf(a), x1 = (int)rintf(b), x2 = (int)rintf(c), x3 = (int)rintf(d);
    return (x0 & 255) | ((x1 & 255) << 8) | ((x2 & 255) << 16) | (x3 << 24);
}

// normalize rows of [z_i; z_j] -> int8 pool [2B, D], global scale 127.
// One wave per row; lane owns 16 contiguous elements -> one int4.
__global__ void normalize_i8_kernel(const float* __restrict__ zi,
                                    const float* __restrict__ zj,
                                    int* __restrict__ pool) {
    int row  = blockIdx.x * 4 + (threadIdx.x >> 6);
    int lane = threadIdx.x & 63;
    const float* src = (row < NB) ? (zi + (size_t)row * ND)
                                  : (zj + (size_t)(row - NB) * ND);
    float v[16];
    float s = 0.f;
#pragma unroll
    for (int seg = 0; seg < 4; ++seg) {
        float4 t = *reinterpret_cast<const float4*>(src + lane * 16 + seg * 4);
        v[seg * 4 + 0] = t.x; v[seg * 4 + 1] = t.y;
        v[seg * 4 + 2] = t.z; v[seg * 4 + 3] = t.w;
        s += t.x * t.x + t.y * t.y + t.z * t.z + t.w * t.w;
    }
#pragma unroll
    for (int off = 32; off >= 1; off >>= 1)
        s += __shfl_xor(s, off, 64);
    float inv = 127.f / fmaxf(sqrtf(s), 1e-12f);

    int4 w;
    w.x = pack4_i8(v[0]*inv,  v[1]*inv,  v[2]*inv,  v[3]*inv);
    w.y = pack4_i8(v[4]*inv,  v[5]*inv,  v[6]*inv,  v[7]*inv);
    w.z = pack4_i8(v[8]*inv,  v[9]*inv,  v[10]*inv, v[11]*inv);
    w.w = pack4_i8(v[12]*inv, v[13]*inv, v[14]*inv, v[15]*inv);
    *reinterpret_cast<int4*>(pool + row * (ND / 4) + lane * 4) = w;
}

// Funnel reduce: v[8] per-lane partials -> each of the 8 values summed over
// all 64 lanes; result: each lane holds one value (value chosen by lane bits
// 5..3), each value present in exactly 8 lanes.
__device__ __forceinline__ float funnel8(const float v[8], int lane) {
    bool b5 = (lane & 32) != 0, b4 = (lane & 16) != 0, b3 = (lane & 8) != 0;
    float s[4], t[2], u;
#pragma unroll
    for (int i = 0; i < 4; ++i) {
        float keep = b5 ? v[2*i+1] : v[2*i];
        float send = b5 ? v[2*i]   : v[2*i+1];
        s[i] = keep + __shfl_xor(send, 32, 64);
    }
#pragma unroll
    for (int i = 0; i < 2; ++i) {
        float keep = b4 ? s[2*i+1] : s[2*i];
        float send = b4 ? s[2*i]   : s[2*i+1];
        t[i] = keep + __shfl_xor(send, 16, 64);
    }
    {
        float keep = b3 ? t[1] : t[0];
        float send = b3 ? t[0] : t[1];
        u = keep + __shfl_xor(send, 8, 64);
    }
    u += __shfl_xor(u, 4, 64);
    u += __shfl_xor(u, 2, 64);
    u += __shfl_xor(u, 1, 64);
    return u;
}

// per-row loss. One wave per row. 32 logical slots: k=0 positive, k=1..30
// negatives, k=31 pad (-1e30). 4 chunks of 8, each funnel-reduced; LSE over
// the 4 per-lane results (each of the 32 values lives in 8 lanes -> /8).
__global__ void loss_kernel(const int* __restrict__ pool,
                            const int* __restrict__ neg_idx,
                            const float* __restrict__ temp_ptr,
                            float* __restrict__ partial) {
    int wave = threadIdx.x >> 6;
    int lane = threadIdx.x & 63;
    int row  = blockIdx.x * 4 + wave;

    const float s2    = 1.f / (127.f * 127.f);
    float inv_t = s2 / temp_ptr[0];

    int af[4];
    {
        int4 araw = *reinterpret_cast<const int4*>(pool + row * 256 + lane * 4);
        af[0] = araw.x; af[1] = araw.y; af[2] = araw.z; af[3] = araw.w;
    }

    int myidx = (lane < NK) ? neg_idx[row * NK + lane] : 0;

    int4 bufA[4], bufB[4];

    auto issue4 = [&](int kc, int4* buf) {
#pragma unroll
        for (int j = 0; j < 4; ++j) {
            int kk = kc + j;
            if (kk < 31) {
                int r = (kk == 0) ? (row + NB) : __shfl(myidx, kk - 1, 64);
                buf[j] = *reinterpret_cast<const int4*>(pool + r * 256 + lane * 4);
            }
        }
    };
    auto dot16 = [&](const int4& rw) -> float {
        int acc = 0;
        acc = __builtin_amdgcn_sdot4(af[0], rw.x, acc, false);
        acc = __builtin_amdgcn_sdot4(af[1], rw.y, acc, false);
        acc = __builtin_amdgcn_sdot4(af[2], rw.z, acc, false);
        acc = __builtin_amdgcn_sdot4(af[3], rw.w, acc, false);
        return (float)acc;
    };

    issue4(0, bufA);
    issue4(4, bufB);

    float r[4];
    float pos_dot = 0.f;
#pragma unroll
    for (int c = 0; c < 4; ++c) {
        float dt[8];
#pragma unroll
        for (int j = 0; j < 4; ++j)
            dt[j] = (c * 8 + j < 31) ? dot16(bufA[j]) : -1e30f;
        if (c < 3) issue4(c * 8 + 8, bufA);
#pragma unroll
        for (int j = 0; j < 4; ++j)
            dt[4 + j] = (c * 8 + 4 + j < 31) ? dot16(bufB[j]) : -1e30f;
        if (c < 3) issue4(c * 8 + 12, bufB);

        if (c == 0) {
            float p = dt[0];
#pragma unroll
            for (int off = 32; off >= 1; off >>= 1)
                p += __shfl_xor(p, off, 64);
            pos_dot = p;
        }
        r[c] = funnel8(dt, lane);
    }

    // scale to logits
    float lr0 = r[0] * inv_t, lr1 = r[1] * inv_t;
    float lr2 = r[2] * inv_t, lr3 = r[3] * inv_t;

    float m = fmaxf(fmaxf(lr0, lr1), fmaxf(lr2, lr3));
#pragma unroll
    for (int off = 32; off >= 1; off >>= 1)
        m = fmaxf(m, __shfl_xor(m, off, 64));

    float e = __expf(lr0 - m) + __expf(lr1 - m)
            + __expf(lr2 - m) + __expf(lr3 - m);
#pragma unroll
    for (int off = 32; off >= 1; off >>= 1)
        e += __shfl_xor(e, off, 64);

    float logit0 = pos_dot * inv_t;
    float loss = (m + logf(e * 0.125f)) - logit0;

    __shared__ float red[4];
    if (lane == 0) red[wave] = loss;
    __syncthreads();
    if (threadIdx.x == 0)
        partial[blockIdx.x] = red[0] + red[1] + red[2] + red[3];
}

#else  // !HAVE_SDOT4 — fp8 fallback (round-5 path)

__device__ __forceinline__ int pack4_fp8(float a, float b, float c, float d) {
    int t = 0;
    t = __builtin_amdgcn_cvt_pk_fp8_f32(a, b, t, false);
    t = __builtin_amdgcn_cvt_pk_fp8_f32(c, d, t, true);
    return t;
}

__global__ void normalize_i8_kernel(const float* __restrict__ zi,
                                    const float* __restrict__ zj,
                                    int* __restrict__ pool) {
    int row  = blockIdx.x * 4 + (threadIdx.x >> 6);
    int lane = threadIdx.x & 63;
    const float* src = (row < NB) ? (zi + (size_t)row * ND)
                                  : (zj + (size_t)(row - NB) * ND);
    float v[16];
    float s = 0.f;
#pragma unroll
    for (int seg = 0; seg < 4; ++seg) {
        float4 t = *reinterpret_cast<const float4*>(src + lane * 16 + seg * 4);
        v[seg*4+0] = t.x; v[seg*4+1] = t.y; v[seg*4+2] = t.z; v[seg*4+3] = t.w;
        s += t.x*t.x + t.y*t.y + t.z*t.z + t.w*t.w;
    }
#pragma unroll
    for (int off = 32; off >= 1; off >>= 1)
        s += __shfl_xor(s, off, 64);
    float inv = 1.f / fmaxf(sqrtf(s), 1e-12f);
    int4 w;
    w.x = pack4_fp8(v[0]*inv,  v[1]*inv,  v[2]*inv,  v[3]*inv);
    w.y = pack4_fp8(v[4]*inv,  v[5]*inv,  v[6]*inv,  v[7]*inv);
    w.z = pack4_fp8(v[8]*inv,  v[9]*inv,  v[10]*inv, v[11]*inv);
    w.w = pack4_fp8(v[12]*inv, v[13]*inv, v[14]*inv, v[15]*inv);
    *reinterpret_cast<int4*>(pool + row * (ND / 4) + lane * 4) = w;
}

__global__ void loss_kernel(const int* __restrict__ pool,
                            const int* __restrict__ neg_idx,
                            const float* __restrict__ temp_ptr,
                            float* __restrict__ partial) {
    int wave = threadIdx.x >> 6;
    int lane = threadIdx.x & 63;
    int row  = blockIdx.x * 4 + wave;
    float inv_t = 1.f / temp_ptr[0];

    float af[16];
    {
        int4 araw = *reinterpret_cast<const int4*>(pool + row * 256 + lane * 4);
        const int* ap = reinterpret_cast<const int*>(&araw);
#pragma unroll
        for (int d = 0; d < 4; ++d) {
            vf2 lo = __builtin_amdgcn_cvt_pk_f32_fp8(ap[d], false);
            vf2 hi = __builtin_amdgcn_cvt_pk_f32_fp8(ap[d], true);
            af[d*4+0] = lo[0]; af[d*4+1] = lo[1];
            af[d*4+2] = hi[0]; af[d*4+3] = hi[1];
        }
    }
    int myidx = (lane < NK) ? neg_idx[row * NK + lane] : 0;
    float dt[31];
#pragma unroll
    for (int kc = 0; kc < 31; kc += 8) {
        int4 raw[8];
#pragma unroll
        for (int j = 0; j < 8; ++j) {
            int kk = kc + j;
            if (kk < 31) {
                int r = (kk == 0) ? (row + NB) : __shfl(myidx, kk - 1, 64);
                raw[j] = *reinterpret_cast<const int4*>(pool + r * 256 + lane * 4);
            }
        }
#pragma unroll
        for (int j = 0; j < 8; ++j) {
            int kk = kc + j;
            if (kk < 31) {
                const int* rp = reinterpret_cast<const int*>(&raw[j]);
                float d0 = 0.f;
#pragma unroll
                for (int d = 0; d < 4; ++d) {
                    vf2 lo = __builtin_amdgcn_cvt_pk_f32_fp8(rp[d], false);
                    vf2 hi = __builtin_amdgcn_cvt_pk_f32_fp8(rp[d], true);
                    d0 += af[d*4+0]*lo[0] + af[d*4+1]*lo[1]
                        + af[d*4+2]*hi[0] + af[d*4+3]*hi[1];
                }
                dt[kk] = d0;
            }
        }
    }
#pragma unroll
    for (int k = 0; k < 31; ++k) {
#pragma unroll
        for (int off = 32; off >= 1; off >>= 1)
            dt[k] += __shfl_xor(dt[k], off, 64);
    }
    float logit0 = dt[0] * inv_t;
    float m = logit0;
#pragma unroll
    for (int k = 1; k < 31; ++k) m = fmaxf(m, dt[k] * inv_t);
    float ssum = 0.f;
#pragma unroll
    for (int k = 0; k < 31; ++k) ssum += __expf(dt[k] * inv_t - m);
    float loss = (m + logf(ssum)) - logit0;

    __shared__ float red[4];
    if (lane == 0) red[wave] = loss;
    __syncthreads();
    if (threadIdx.x == 0)
        partial[blockIdx.x] = red[0] + red[1] + red[2] + red[3];
}

#endif // HAVE_SDOT4

// ---------------------------------------------------------------------------
// f32 fallback (only if ws too small for the pool)
// ---------------------------------------------------------------------------
__global__ void norms_kernel(const float* __restrict__ zi,
                             const float* __restrict__ zj,
                             float* __restrict__ inv_norm) {
    int row  = blockIdx.x * 4 + (threadIdx.x >> 6);
    int lane = threadIdx.x & 63;
    if (row >= 2 * NB) return;
    const float* src = (row < NB) ? (zi + (size_t)row * ND)
                                  : (zj + (size_t)(row - NB) * ND);
    float s = 0.f;
#pragma unroll
    for (int seg = 0; seg < 4; ++seg) {
        float4 v = *reinterpret_cast<const float4*>(src + seg * 256 + lane * 4);
        s += v.x*v.x + v.y*v.y + v.z*v.z + v.w*v.w;
    }
#pragma unroll
    for (int off = 32; off >= 1; off >>= 1)
        s += __shfl_xor(s, off, 64);
    if (lane == 0)
        inv_norm[row] = 1.f / fmaxf(sqrtf(s), 1e-12f);
}

__global__ void loss_kernel_f32(const float* __restrict__ zi,
                                const float* __restrict__ zj,
                                const int*   __restrict__ neg_idx,
                                const float* __restrict__ temp_ptr,
                                const float* __restrict__ inv_norm,
                                float* __restrict__ partial) {
    int wave = threadIdx.x >> 6;
    int lane = threadIdx.x & 63;
    int row  = blockIdx.x * 4 + wave;
    float inv_t = 1.f / temp_ptr[0];
    const float* a = zi + (size_t)row * ND;
    float4 av[4];
#pragma unroll
    for (int seg = 0; seg < 4; ++seg)
        av[seg] = *reinterpret_cast<const float4*>(a + seg * 256 + lane * 4);
    float inv_a = inv_norm[row];
    float m = -INFINITY, ssum = 0.f, logit0 = 0.f;
    for (int k = -1; k < NK; ++k) {
        int r = (k < 0) ? (row + NB) : neg_idx[row * NK + k];
        const float* bp = (r < NB) ? (zi + (size_t)r * ND)
                                   : (zj + (size_t)(r - NB) * ND);
        float inv_b = inv_norm[r];
        float dot = 0.f;
#pragma unroll
        for (int seg = 0; seg < 4; ++seg) {
            float4 bv = *reinterpret_cast<const float4*>(bp + seg * 256 + lane * 4);
            dot += av[seg].x*bv.x + av[seg].y*bv.y + av[seg].z*bv.z + av[seg].w*bv.w;
        }
#pragma unroll
        for (int off = 32; off >= 1; off >>= 1)
            dot += __shfl_xor(dot, off, 64);
        float logit = dot * inv_a * inv_b * inv_t;
        if (k < 0) logit0 = logit;
        if (logit > m) { ssum = ssum * __expf(m - logit) + 1.f; m = logit; }
        else           { ssum += __expf(logit - m); }
    }
    float loss = (m + logf(ssum)) - logit0;
    __shared__ float red[4];
    if (lane == 0) red[wave] = loss;
    __syncthreads();
    if (threadIdx.x == 0)
        partial[blockIdx.x] = red[0] + red[1] + red[2] + red[3];
}

// ---------------------------------------------------------------------------
// final reduction of per-block partials -> mean loss
// ---------------------------------------------------------------------------
__global__ void reduce_kernel(const float* __restrict__ partial, int n,
                              float* __restrict__ out) {
    float s = 0.f;
    for (int i = threadIdx.x; i < n; i += 256) s += partial[i];
#pragma unroll
    for (int off = 32; off >= 1; off >>= 1)
        s += __shfl_xor(s, off, 64);
    __shared__ float lds[4];
    int wave = threadIdx.x >> 6, lane = threadIdx.x & 63;
    if (lane == 0) lds[wave] = s;
    __syncthreads();
    if (threadIdx.x == 0)
        out[0] = (lds[0] + lds[1] + lds[2] + lds[3]) * (1.f / (float)NB);
}

extern "C" void kernel_launch(void* const* d_in, const int* in_sizes, int n_in,
                              void* d_out, int out_size, void* d_ws, size_t ws_size,
                              hipStream_t stream) {
    const float* zi      = (const float*)d_in[0];
    const float* zj      = (const float*)d_in[1];
    const float* temp    = (const float*)d_in[2];
    const int*   neg_idx = (const int*)d_in[3];
    float* out = (float*)d_out;

    const size_t pool_bytes    = (size_t)2 * NB * ND;            // 16 MiB
    const size_t partial_bytes = (size_t)(NB / 4) * sizeof(float);

    if (ws_size >= pool_bytes + partial_bytes) {
        int*   pool    = (int*)d_ws;
        float* partial = (float*)((char*)d_ws + pool_bytes);

        normalize_i8_kernel<<<(2 * NB) / 4, 256, 0, stream>>>(zi, zj, pool);
        loss_kernel<<<NB / 4, 256, 0, stream>>>(pool, neg_idx, temp, partial);
        reduce_kernel<<<1, 256, 0, stream>>>(partial, NB / 4, out);
    } else {
        float* inv_norm = (float*)d_ws;
        float* partial  = inv_norm + 2 * NB;

        norms_kernel<<<(2 * NB) / 4, 256, 0, stream>>>(zi, zj, inv_norm);
        loss_kernel_f32<<<NB / 4, 256, 0, stream>>>(zi, zj, neg_idx, temp,
                                                    inv_norm, partial);
        reduce_kernel<<<1, 256, 0, stream>>>(partial, NB / 4, out);
    }
}

// Round 7
// 41.688 us; speedup vs baseline: 1.5228x; 1.2447x over previous
//
#include <hip/hip_runtime.h>
#include <math.h>

constexpr int NB = 8192;   // batch
constexpr int ND = 1024;   // dim
constexpr int NK = 30;     // negatives
constexpr int RS = ND / 4; // row stride in ints (256)

#if defined(__has_builtin)
#  if __has_builtin(__builtin_amdgcn_sdot4)
#    define HAVE_SDOT4 1
#  endif
#endif
#ifndef HAVE_SDOT4
#  define HAVE_SDOT4 0
#endif

__device__ __forceinline__ int SDOT4(int a, int b, int acc) {
#if HAVE_SDOT4
    return __builtin_amdgcn_sdot4(a, b, acc, false);
#else
    return acc + (int)(signed char)(a)        * (int)(signed char)(b)
               + (int)(signed char)(a >> 8)   * (int)(signed char)(b >> 8)
               + (int)(signed char)(a >> 16)  * (int)(signed char)(b >> 16)
               + (int)(a >> 24)               * (int)(b >> 24);
#endif
}

__device__ __forceinline__ int pack4_i8(float a, float b, float c, float d) {
    int x0 = (int)rintf(a), x1 = (int)rintf(b), x2 = (int)rintf(c), x3 = (int)rintf(d);
    return (x0 & 255) | ((x1 & 255) << 8) | ((x2 & 255) << 16) | (x3 << 24);
}

// ---------------------------------------------------------------------------
// Kernel 1: normalize rows of [z_i; z_j] -> int8 pool [2B, D], scale 127.
// One wave per row; lane owns 16 contiguous elements -> one int4.
// ---------------------------------------------------------------------------
__global__ void normalize_i8_kernel(const float* __restrict__ zi,
                                    const float* __restrict__ zj,
                                    int* __restrict__ pool) {
    int row  = blockIdx.x * 4 + (threadIdx.x >> 6);
    int lane = threadIdx.x & 63;
    const float* src = (row < NB) ? (zi + (size_t)row * ND)
                                  : (zj + (size_t)(row - NB) * ND);
    float v[16];
    float s = 0.f;
#pragma unroll
    for (int seg = 0; seg < 4; ++seg) {
        float4 t = *reinterpret_cast<const float4*>(src + lane * 16 + seg * 4);
        v[seg * 4 + 0] = t.x; v[seg * 4 + 1] = t.y;
        v[seg * 4 + 2] = t.z; v[seg * 4 + 3] = t.w;
        s += t.x * t.x + t.y * t.y + t.z * t.z + t.w * t.w;
    }
#pragma unroll
    for (int off = 32; off >= 1; off >>= 1)
        s += __shfl_xor(s, off, 64);
    float inv = 127.f / fmaxf(sqrtf(s), 1e-12f);

    int4 w;
    w.x = pack4_i8(v[0]*inv,  v[1]*inv,  v[2]*inv,  v[3]*inv);
    w.y = pack4_i8(v[4]*inv,  v[5]*inv,  v[6]*inv,  v[7]*inv);
    w.z = pack4_i8(v[8]*inv,  v[9]*inv,  v[10]*inv, v[11]*inv);
    w.w = pack4_i8(v[12]*inv, v[13]*inv, v[14]*inv, v[15]*inv);
    *reinterpret_cast<int4*>(pool + (size_t)row * RS + lane * 4) = w;
}

// ---------------------------------------------------------------------------
// Kernel 2: XCD-sliced partial dots.
// chunk c = blockIdx.x & 7  (round-robin dispatch => chunk c stays on XCD c,
// whose 2 MB pool slice becomes L2-resident). Wave handles (row, c):
// 32 slots (slot 0 = positive row+NB, 1..30 = negatives, 31 = pad).
// Lane split: g = lane>>3 selects slot-within-round, p = lane&7 selects the
// 16B fragment of the 128B chunk. Exact int partials -> partial[row][c][k].
// ---------------------------------------------------------------------------
__global__ void loss_chunk_kernel(const int* __restrict__ pool,
                                  const int* __restrict__ neg_idx,
                                  int* __restrict__ partial) {
    int wave = threadIdx.x >> 6;
    int lane = threadIdx.x & 63;
    int c    = blockIdx.x & 7;
    int row  = (blockIdx.x >> 3) * 4 + wave;
    int g    = lane >> 3;
    int p    = lane & 7;

    const int* cbase = pool + c * 32 + p * 4;

    int4 a4 = *reinterpret_cast<const int4*>(cbase + (size_t)row * RS);

    int myidx = (lane < NK) ? neg_idx[row * NK + lane] : 0;

    // gather 4 targets (slots g, 8+g, 16+g, 24+g)
    int4 b4[4];
#pragma unroll
    for (int t = 0; t < 4; ++t) {
        int s = t * 8 + g;
        int r = (s == 0) ? (row + NB)
              : (s < 31) ? __shfl(myidx, s - 1, 64)
                         : 0;                       // pad slot -> row 0 (masked later)
        b4[t] = *reinterpret_cast<const int4*>(cbase + (size_t)r * RS);
    }

    int d0 = 0, d1 = 0, d2 = 0, d3 = 0;
    d0 = SDOT4(a4.x, b4[0].x, d0); d0 = SDOT4(a4.y, b4[0].y, d0);
    d0 = SDOT4(a4.z, b4[0].z, d0); d0 = SDOT4(a4.w, b4[0].w, d0);
    d1 = SDOT4(a4.x, b4[1].x, d1); d1 = SDOT4(a4.y, b4[1].y, d1);
    d1 = SDOT4(a4.z, b4[1].z, d1); d1 = SDOT4(a4.w, b4[1].w, d1);
    d2 = SDOT4(a4.x, b4[2].x, d2); d2 = SDOT4(a4.y, b4[2].y, d2);
    d2 = SDOT4(a4.z, b4[2].z, d2); d2 = SDOT4(a4.w, b4[2].w, d2);
    d3 = SDOT4(a4.x, b4[3].x, d3); d3 = SDOT4(a4.y, b4[3].y, d3);
    d3 = SDOT4(a4.z, b4[3].z, d3); d3 = SDOT4(a4.w, b4[3].w, d3);

    // reduce the 8 fragment-lanes of each slot (exact int adds)
#pragma unroll
    for (int off = 1; off <= 4; off <<= 1) {
        d0 += __shfl_xor(d0, off, 64);
        d1 += __shfl_xor(d1, off, 64);
        d2 += __shfl_xor(d2, off, 64);
        d3 += __shfl_xor(d3, off, 64);
    }

    // writer: lane with p==t, g -> slot t*8+g
    if (p < 4) {
        int val = (p == 0) ? d0 : (p == 1) ? d1 : (p == 2) ? d2 : d3;
        partial[(size_t)row * 256 + c * 32 + p * 8 + g] = val;
    }
}

// ---------------------------------------------------------------------------
// Kernel 3: per-row chunk-sum + logsumexp. One wave per row.
// partial layout [row][c][k]: lane reads int4 at lane*4 -> chunk c=lane>>3,
// slots (lane&7)*4..+3. Sum chunks via xor-8/16/32; LSE via xor-1/2/4.
// ---------------------------------------------------------------------------
__global__ void lse_kernel(const int* __restrict__ partial,
                           const float* __restrict__ temp_ptr,
                           float* __restrict__ block_part) {
    int wave = threadIdx.x >> 6;
    int lane = threadIdx.x & 63;
    int row  = blockIdx.x * 4 + wave;

    float inv_t = 1.f / (127.f * 127.f * temp_ptr[0]);

    int4 v = *reinterpret_cast<const int4*>(partial + (size_t)row * 256 + lane * 4);
    int s0 = v.x, s1 = v.y, s2 = v.z, s3 = v.w;
#pragma unroll
    for (int off = 8; off <= 32; off <<= 1) {
        s0 += __shfl_xor(s0, off, 64);
        s1 += __shfl_xor(s1, off, 64);
        s2 += __shfl_xor(s2, off, 64);
        s3 += __shfl_xor(s3, off, 64);
    }
    float l0 = s0 * inv_t, l1 = s1 * inv_t, l2 = s2 * inv_t, l3 = s3 * inv_t;
    if ((lane & 7) == 7) l3 = -1e30f;          // slot 31 is padding

    float m = fmaxf(fmaxf(l0, l1), fmaxf(l2, l3));
#pragma unroll
    for (int off = 1; off <= 4; off <<= 1)
        m = fmaxf(m, __shfl_xor(m, off, 64));

    float e = __expf(l0 - m) + __expf(l1 - m) + __expf(l2 - m) + __expf(l3 - m);
#pragma unroll
    for (int off = 1; off <= 4; off <<= 1)
        e += __shfl_xor(e, off, 64);

    float logit0 = __shfl(l0, lane & 56, 64);  // slot 0 from group-base lane
    float loss = (m + logf(e)) - logit0;

    __shared__ float red[4];
    if (lane == 0) red[wave] = loss;
    __syncthreads();
    if (threadIdx.x == 0)
        block_part[blockIdx.x] = red[0] + red[1] + red[2] + red[3];
}

// ---------------------------------------------------------------------------
// Kernel 4: final reduction of per-block partials -> mean loss
// ---------------------------------------------------------------------------
__global__ void reduce_kernel(const float* __restrict__ partial, int n,
                              float* __restrict__ out) {
    float s = 0.f;
    for (int i = threadIdx.x; i < n; i += 256) s += partial[i];
#pragma unroll
    for (int off = 32; off >= 1; off >>= 1)
        s += __shfl_xor(s, off, 64);
    __shared__ float lds[4];
    int wave = threadIdx.x >> 6, lane = threadIdx.x & 63;
    if (lane == 0) lds[wave] = s;
    __syncthreads();
    if (threadIdx.x == 0)
        out[0] = (lds[0] + lds[1] + lds[2] + lds[3]) * (1.f / (float)NB);
}

// ---------------------------------------------------------------------------
// f32 fallback (only if ws too small for pool + partials)
// ---------------------------------------------------------------------------
__global__ void norms_kernel(const float* __restrict__ zi,
                             const float* __restrict__ zj,
                             float* __restrict__ inv_norm) {
    int row  = blockIdx.x * 4 + (threadIdx.x >> 6);
    int lane = threadIdx.x & 63;
    if (row >= 2 * NB) return;
    const float* src = (row < NB) ? (zi + (size_t)row * ND)
                                  : (zj + (size_t)(row - NB) * ND);
    float s = 0.f;
#pragma unroll
    for (int seg = 0; seg < 4; ++seg) {
        float4 v = *reinterpret_cast<const float4*>(src + seg * 256 + lane * 4);
        s += v.x*v.x + v.y*v.y + v.z*v.z + v.w*v.w;
    }
#pragma unroll
    for (int off = 32; off >= 1; off >>= 1)
        s += __shfl_xor(s, off, 64);
    if (lane == 0)
        inv_norm[row] = 1.f / fmaxf(sqrtf(s), 1e-12f);
}

__global__ void loss_kernel_f32(const float* __restrict__ zi,
                                const float* __restrict__ zj,
                                const int*   __restrict__ neg_idx,
                                const float* __restrict__ temp_ptr,
                                const float* __restrict__ inv_norm,
                                float* __restrict__ partial) {
    int wave = threadIdx.x >> 6;
    int lane = threadIdx.x & 63;
    int row  = blockIdx.x * 4 + wave;
    float inv_t = 1.f / temp_ptr[0];
    const float* a = zi + (size_t)row * ND;
    float4 av[4];
#pragma unroll
    for (int seg = 0; seg < 4; ++seg)
        av[seg] = *reinterpret_cast<const float4*>(a + seg * 256 + lane * 4);
    float inv_a = inv_norm[row];
    float m = -INFINITY, ssum = 0.f, logit0 = 0.f;
    for (int k = -1; k < NK; ++k) {
        int r = (k < 0) ? (row + NB) : neg_idx[row * NK + k];
        const float* bp = (r < NB) ? (zi + (size_t)r * ND)
                                   : (zj + (size_t)(r - NB) * ND);
        float inv_b = inv_norm[r];
        float dot = 0.f;
#pragma unroll
        for (int seg = 0; seg < 4; ++seg) {
            float4 bv = *reinterpret_cast<const float4*>(bp + seg * 256 + lane * 4);
            dot += av[seg].x*bv.x + av[seg].y*bv.y + av[seg].z*bv.z + av[seg].w*bv.w;
        }
#pragma unroll
        for (int off = 32; off >= 1; off >>= 1)
            dot += __shfl_xor(dot, off, 64);
        float logit = dot * inv_a * inv_b * inv_t;
        if (k < 0) logit0 = logit;
        if (logit > m) { ssum = ssum * __expf(m - logit) + 1.f; m = logit; }
        else           { ssum += __expf(logit - m); }
    }
    float loss = (m + logf(ssum)) - logit0;
    __shared__ float red[4];
    if (lane == 0) red[wave] = loss;
    __syncthreads();
    if (threadIdx.x == 0)
        partial[blockIdx.x] = red[0] + red[1] + red[2] + red[3];
}

extern "C" void kernel_launch(void* const* d_in, const int* in_sizes, int n_in,
                              void* d_out, int out_size, void* d_ws, size_t ws_size,
                              hipStream_t stream) {
    const float* zi      = (const float*)d_in[0];
    const float* zj      = (const float*)d_in[1];
    const float* temp    = (const float*)d_in[2];
    const int*   neg_idx = (const int*)d_in[3];
    float* out = (float*)d_out;

    const size_t pool_bytes  = (size_t)2 * NB * ND;                 // 16 MiB
    const size_t part_bytes  = (size_t)NB * 256 * sizeof(int);      //  8 MiB
    const size_t block_bytes = (size_t)(NB / 4) * sizeof(float);

    if (ws_size >= pool_bytes + part_bytes + block_bytes) {
        int*   pool       = (int*)d_ws;
        int*   partial    = (int*)((char*)d_ws + pool_bytes);
        float* block_part = (float*)((char*)d_ws + pool_bytes + part_bytes);

        normalize_i8_kernel<<<(2 * NB) / 4, 256, 0, stream>>>(zi, zj, pool);
        loss_chunk_kernel<<<(NB / 4) * 8, 256, 0, stream>>>(pool, neg_idx, partial);
        lse_kernel<<<NB / 4, 256, 0, stream>>>(partial, temp, block_part);
        reduce_kernel<<<1, 256, 0, stream>>>(block_part, NB / 4, out);
    } else {
        float* inv_norm = (float*)d_ws;
        float* partial  = inv_norm + 2 * NB;

        norms_kernel<<<(2 * NB) / 4, 256, 0, stream>>>(zi, zj, inv_norm);
        loss_kernel_f32<<<NB / 4, 256, 0, stream>>>(zi, zj, neg_idx, temp,
                                                    inv_norm, partial);
        reduce_kernel<<<1, 256, 0, stream>>>(partial, NB / 4, out);
    }
}

// Round 8
// 40.337 us; speedup vs baseline: 1.5738x; 1.0335x over previous
//
#include <hip/hip_runtime.h>
#include <math.h>

constexpr int NB = 8192;   // batch
constexpr int ND = 1024;   // dim
constexpr int NK = 30;     // negatives
constexpr int RS = ND / 4; // row stride in ints (256)

#if defined(__has_builtin)
#  if __has_builtin(__builtin_amdgcn_sdot4)
#    define HAVE_SDOT4 1
#  endif
#endif
#ifndef HAVE_SDOT4
#  define HAVE_SDOT4 0
#endif

__device__ __forceinline__ int SDOT4(int a, int b, int acc) {
#if HAVE_SDOT4
    return __builtin_amdgcn_sdot4(a, b, acc, false);
#else
    return acc + (int)(signed char)(a)        * (int)(signed char)(b)
               + (int)(signed char)(a >> 8)   * (int)(signed char)(b >> 8)
               + (int)(signed char)(a >> 16)  * (int)(signed char)(b >> 16)
               + (int)(a >> 24)               * (int)(b >> 24);
#endif
}

__device__ __forceinline__ int pack4_i8(float a, float b, float c, float d) {
    int x0 = (int)rintf(a), x1 = (int)rintf(b), x2 = (int)rintf(c), x3 = (int)rintf(d);
    return (x0 & 255) | ((x1 & 255) << 8) | ((x2 & 255) << 16) | (x3 << 24);
}

// ---------------------------------------------------------------------------
// Kernel 1: normalize rows of [z_i; z_j] -> int8 pool [2B, D], scale 127.
// Also zero-inits the logits accumulator (64 ints per block, 4096 blocks
// = NB*32 ints), stream-ordered before loss_chunk's atomics.
// ---------------------------------------------------------------------------
__global__ void normalize_i8_kernel(const float* __restrict__ zi,
                                    const float* __restrict__ zj,
                                    int* __restrict__ pool,
                                    int* __restrict__ logits) {
    if (threadIdx.x < 64)
        logits[blockIdx.x * 64 + threadIdx.x] = 0;

    int row  = blockIdx.x * 4 + (threadIdx.x >> 6);
    int lane = threadIdx.x & 63;
    const float* src = (row < NB) ? (zi + (size_t)row * ND)
                                  : (zj + (size_t)(row - NB) * ND);
    float v[16];
    float s = 0.f;
#pragma unroll
    for (int seg = 0; seg < 4; ++seg) {
        float4 t = *reinterpret_cast<const float4*>(src + lane * 16 + seg * 4);
        v[seg * 4 + 0] = t.x; v[seg * 4 + 1] = t.y;
        v[seg * 4 + 2] = t.z; v[seg * 4 + 3] = t.w;
        s += t.x * t.x + t.y * t.y + t.z * t.z + t.w * t.w;
    }
#pragma unroll
    for (int off = 32; off >= 1; off >>= 1)
        s += __shfl_xor(s, off, 64);
    float inv = 127.f / fmaxf(sqrtf(s), 1e-12f);

    int4 w;
    w.x = pack4_i8(v[0]*inv,  v[1]*inv,  v[2]*inv,  v[3]*inv);
    w.y = pack4_i8(v[4]*inv,  v[5]*inv,  v[6]*inv,  v[7]*inv);
    w.z = pack4_i8(v[8]*inv,  v[9]*inv,  v[10]*inv, v[11]*inv);
    w.w = pack4_i8(v[12]*inv, v[13]*inv, v[14]*inv, v[15]*inv);
    *reinterpret_cast<int4*>(pool + (size_t)row * RS + lane * 4) = w;
}

// ---------------------------------------------------------------------------
// Kernel 2: XCD-sliced partial dots, folded via device-scope int atomics.
// chunk c = blockIdx.x & 7 (round-robin dispatch => chunk c stays on XCD c,
// 2 MB pool slice L2-resident). 32 slots: 0 = positive, 1..30 = negatives,
// 31 = pad. g = lane>>3 slot-in-round, p = lane&7 16B fragment of the 128B
// chunk. Exact int partials accumulated into logits[row][slot].
// ---------------------------------------------------------------------------
__global__ void loss_chunk_kernel(const int* __restrict__ pool,
                                  const int* __restrict__ neg_idx,
                                  int* __restrict__ logits) {
    int wave = threadIdx.x >> 6;
    int lane = threadIdx.x & 63;
    int c    = blockIdx.x & 7;
    int row  = (blockIdx.x >> 3) * 4 + wave;
    int g    = lane >> 3;
    int p    = lane & 7;

    // start the index load first: it heads the gather dependency chain
    int myidx = (lane < NK) ? neg_idx[row * NK + lane] : 0;

    const int* cbase = pool + c * 32 + p * 4;
    int4 a4 = *reinterpret_cast<const int4*>(cbase + (size_t)row * RS);

    // gather 4 targets (slots g, 8+g, 16+g, 24+g)
    int4 b4[4];
#pragma unroll
    for (int t = 0; t < 4; ++t) {
        int s = t * 8 + g;
        int r = (s == 0) ? (row + NB)
              : (s < 31) ? __shfl(myidx, s - 1, 64)
                         : 0;                       // pad slot (masked in lse)
        b4[t] = *reinterpret_cast<const int4*>(cbase + (size_t)r * RS);
    }

    int d0 = 0, d1 = 0, d2 = 0, d3 = 0;
    d0 = SDOT4(a4.x, b4[0].x, d0); d0 = SDOT4(a4.y, b4[0].y, d0);
    d0 = SDOT4(a4.z, b4[0].z, d0); d0 = SDOT4(a4.w, b4[0].w, d0);
    d1 = SDOT4(a4.x, b4[1].x, d1); d1 = SDOT4(a4.y, b4[1].y, d1);
    d1 = SDOT4(a4.z, b4[1].z, d1); d1 = SDOT4(a4.w, b4[1].w, d1);
    d2 = SDOT4(a4.x, b4[2].x, d2); d2 = SDOT4(a4.y, b4[2].y, d2);
    d2 = SDOT4(a4.z, b4[2].z, d2); d2 = SDOT4(a4.w, b4[2].w, d2);
    d3 = SDOT4(a4.x, b4[3].x, d3); d3 = SDOT4(a4.y, b4[3].y, d3);
    d3 = SDOT4(a4.z, b4[3].z, d3); d3 = SDOT4(a4.w, b4[3].w, d3);

    // reduce the 8 fragment-lanes of each slot (exact int adds)
#pragma unroll
    for (int off = 1; off <= 4; off <<= 1) {
        d0 += __shfl_xor(d0, off, 64);
        d1 += __shfl_xor(d1, off, 64);
        d2 += __shfl_xor(d2, off, 64);
        d3 += __shfl_xor(d3, off, 64);
    }

    // fold chunks: device-scope int atomic (associative -> deterministic)
    if (p < 4) {
        int val = (p == 0) ? d0 : (p == 1) ? d1 : (p == 2) ? d2 : d3;
        atomicAdd(&logits[row * 32 + p * 8 + g], val);
    }
}

// ---------------------------------------------------------------------------
// Kernel 3: logsumexp. 2 rows per wave (32 lanes each), 8 rows per block.
// ---------------------------------------------------------------------------
__global__ void lse_kernel(const int* __restrict__ logits,
                           const float* __restrict__ temp_ptr,
                           float* __restrict__ block_part) {
    int wave = threadIdx.x >> 6;
    int lane = threadIdx.x & 63;
    int slot = lane & 31;
    int row  = blockIdx.x * 8 + wave * 2 + (lane >> 5);

    float inv_t = 1.f / (127.f * 127.f * temp_ptr[0]);

    float l = (slot < 31) ? logits[row * 32 + slot] * inv_t : -1e30f;

    float m = l;
#pragma unroll
    for (int off = 1; off <= 16; off <<= 1)
        m = fmaxf(m, __shfl_xor(m, off, 64));
    float e = __expf(l - m);
#pragma unroll
    for (int off = 1; off <= 16; off <<= 1)
        e += __shfl_xor(e, off, 64);

    float l0   = __shfl(l, lane & 32, 64);      // slot 0 of own half
    float loss = (m + logf(e)) - l0;
    float loss2 = __shfl(loss, 32, 64);         // other half's loss

    __shared__ float red[4];
    if (lane == 0) red[wave] = loss + loss2;
    __syncthreads();
    if (threadIdx.x == 0)
        block_part[blockIdx.x] = red[0] + red[1] + red[2] + red[3];
}

// ---------------------------------------------------------------------------
// Kernel 4: final reduction of per-block partials -> mean loss
// ---------------------------------------------------------------------------
__global__ void reduce_kernel(const float* __restrict__ partial, int n,
                              float* __restrict__ out) {
    float s = 0.f;
    for (int i = threadIdx.x; i < n; i += 256) s += partial[i];
#pragma unroll
    for (int off = 32; off >= 1; off >>= 1)
        s += __shfl_xor(s, off, 64);
    __shared__ float lds[4];
    int wave = threadIdx.x >> 6, lane = threadIdx.x & 63;
    if (lane == 0) lds[wave] = s;
    __syncthreads();
    if (threadIdx.x == 0)
        out[0] = (lds[0] + lds[1] + lds[2] + lds[3]) * (1.f / (float)NB);
}

// ---------------------------------------------------------------------------
// f32 fallback (only if ws too small for pool + logits)
// ---------------------------------------------------------------------------
__global__ void norms_kernel(const float* __restrict__ zi,
                             const float* __restrict__ zj,
                             float* __restrict__ inv_norm) {
    int row  = blockIdx.x * 4 + (threadIdx.x >> 6);
    int lane = threadIdx.x & 63;
    if (row >= 2 * NB) return;
    const float* src = (row < NB) ? (zi + (size_t)row * ND)
                                  : (zj + (size_t)(row - NB) * ND);
    float s = 0.f;
#pragma unroll
    for (int seg = 0; seg < 4; ++seg) {
        float4 v = *reinterpret_cast<const float4*>(src + seg * 256 + lane * 4);
        s += v.x*v.x + v.y*v.y + v.z*v.z + v.w*v.w;
    }
#pragma unroll
    for (int off = 32; off >= 1; off >>= 1)
        s += __shfl_xor(s, off, 64);
    if (lane == 0)
        inv_norm[row] = 1.f / fmaxf(sqrtf(s), 1e-12f);
}

__global__ void loss_kernel_f32(const float* __restrict__ zi,
                                const float* __restrict__ zj,
                                const int*   __restrict__ neg_idx,
                                const float* __restrict__ temp_ptr,
                                const float* __restrict__ inv_norm,
                                float* __restrict__ partial) {
    int wave = threadIdx.x >> 6;
    int lane = threadIdx.x & 63;
    int row  = blockIdx.x * 4 + wave;
    float inv_t = 1.f / temp_ptr[0];
    const float* a = zi + (size_t)row * ND;
    float4 av[4];
#pragma unroll
    for (int seg = 0; seg < 4; ++seg)
        av[seg] = *reinterpret_cast<const float4*>(a + seg * 256 + lane * 4);
    float inv_a = inv_norm[row];
    float m = -INFINITY, ssum = 0.f, logit0 = 0.f;
    for (int k = -1; k < NK; ++k) {
        int r = (k < 0) ? (row + NB) : neg_idx[row * NK + k];
        const float* bp = (r < NB) ? (zi + (size_t)r * ND)
                                   : (zj + (size_t)(r - NB) * ND);
        float inv_b = inv_norm[r];
        float dot = 0.f;
#pragma unroll
        for (int seg = 0; seg < 4; ++seg) {
            float4 bv = *reinterpret_cast<const float4*>(bp + seg * 256 + lane * 4);
            dot += av[seg].x*bv.x + av[seg].y*bv.y + av[seg].z*bv.z + av[seg].w*bv.w;
        }
#pragma unroll
        for (int off = 32; off >= 1; off >>= 1)
            dot += __shfl_xor(dot, off, 64);
        float logit = dot * inv_a * inv_b * inv_t;
        if (k < 0) logit0 = logit;
        if (logit > m) { ssum = ssum * __expf(m - logit) + 1.f; m = logit; }
        else           { ssum += __expf(logit - m); }
    }
    float loss = (m + logf(ssum)) - logit0;
    __shared__ float red[4];
    if (lane == 0) red[wave] = loss;
    __syncthreads();
    if (threadIdx.x == 0)
        partial[blockIdx.x] = red[0] + red[1] + red[2] + red[3];
}

extern "C" void kernel_launch(void* const* d_in, const int* in_sizes, int n_in,
                              void* d_out, int out_size, void* d_ws, size_t ws_size,
                              hipStream_t stream) {
    const float* zi      = (const float*)d_in[0];
    const float* zj      = (const float*)d_in[1];
    const float* temp    = (const float*)d_in[2];
    const int*   neg_idx = (const int*)d_in[3];
    float* out = (float*)d_out;

    const size_t pool_bytes   = (size_t)2 * NB * ND;                // 16 MiB
    const size_t logits_bytes = (size_t)NB * 32 * sizeof(int);      //  1 MiB
    const size_t block_bytes  = (size_t)(NB / 8) * sizeof(float);

    if (ws_size >= pool_bytes + logits_bytes + block_bytes) {
        int*   pool       = (int*)d_ws;
        int*   logits     = (int*)((char*)d_ws + pool_bytes);
        float* block_part = (float*)((char*)d_ws + pool_bytes + logits_bytes);

        normalize_i8_kernel<<<(2 * NB) / 4, 256, 0, stream>>>(zi, zj, pool, logits);
        loss_chunk_kernel<<<(NB / 4) * 8, 256, 0, stream>>>(pool, neg_idx, logits);
        lse_kernel<<<NB / 8, 256, 0, stream>>>(logits, temp, block_part);
        reduce_kernel<<<1, 256, 0, stream>>>(block_part, NB / 8, out);
    } else {
        float* inv_norm = (float*)d_ws;
        float* partial  = inv_norm + 2 * NB;

        norms_kernel<<<(2 * NB) / 4, 256, 0, stream>>>(zi, zj, inv_norm);
        loss_kernel_f32<<<NB / 4, 256, 0, stream>>>(zi, zj, neg_idx, temp,
                                                    inv_norm, partial);
        reduce_kernel<<<1, 256, 0, stream>>>(partial, NB / 4, out);
    }
}